// Round 9
// baseline (4669.628 us; speedup 1.0000x reference)
//
#include <hip/hip_runtime.h>
#include <stdint.h>

// ---------------------------------------------------------------------------
// Types / helpers
// ---------------------------------------------------------------------------
typedef short short8 __attribute__((ext_vector_type(8)));
typedef float float4v __attribute__((ext_vector_type(4)));

__device__ __forceinline__ float b2f(short s) {
    return __uint_as_float(((unsigned)(unsigned short)s) << 16);
}
__device__ __forceinline__ short f2b(float f) {
    unsigned u = __float_as_uint(f);
    unsigned r = (u + 0x7fffu + ((u >> 16) & 1u)) >> 16;
    return (short)r;
}

// ---------------------------------------------------------------------------
// fp32 -> bf16 convert (grid-stride)
// ---------------------------------------------------------------------------
__global__ void k_f32_to_bf16(const float* __restrict__ in, short* __restrict__ out, int n) {
    int i = blockIdx.x * blockDim.x + threadIdx.x;
    int stride = gridDim.x * blockDim.x;
    for (; i < n; i += stride) out[i] = f2b(in[i]);
}

// Fused converter for the 8 contiguous weight buffers
__global__ void k_cvt_weights(const float* __restrict__ s0, const float* __restrict__ s1,
                              const float* __restrict__ s2, const float* __restrict__ s3,
                              const float* __restrict__ s4, const float* __restrict__ s5,
                              const float* __restrict__ s6, const float* __restrict__ s7,
                              short* __restrict__ dst) {
    int i = blockIdx.x * blockDim.x + threadIdx.x;
    int stride = gridDim.x * blockDim.x;
    for (; i < 9961472; i += stride) {
        float v;
        if      (i <  262144) v = s0[i];
        else if (i <  524288) v = s1[i -  262144];
        else if (i < 1048576) v = s2[i -  524288];
        else if (i < 1572864) v = s3[i - 1048576];
        else if (i < 2621440) v = s4[i - 1572864];
        else if (i < 3670016) v = s5[i - 2621440];
        else if (i < 5767168) v = s6[i - 3670016];
        else                  v = s7[i - 5767168];
        dst[i] = f2b(v);
    }
}

// w_c1 [512][1024][3] -> bf16 [512][3*1024]
__global__ void k_wc1_tr(const float* __restrict__ in, short* __restrict__ out) {
    int i = blockIdx.x * blockDim.x + threadIdx.x;
    if (i >= 512 * 3072) return;
    int c = i / 3072, rr = i % 3072, dk = rr / 1024, h = rr % 1024;
    out[i] = f2b(in[(c * 1024 + h) * 3 + dk]);
}

__global__ void k_bias_sum(const float* __restrict__ a, const float* __restrict__ b,
                           float* __restrict__ o, int n) {
    int i = blockIdx.x * blockDim.x + threadIdx.x;
    if (i < n) o[i] = a[i] + b[i];
}

// ---------------------------------------------------------------------------
// Generic batched GEMM:  C[m][n] = act( sum_k A[m][k]*B[n][k] + bias[n] )
// Staging via global_load_lds width=16 (async DMA, no VGPR roundtrip).
// XOR de-conflict swizzle applied on the SOURCE side (per-lane gptr), so
// LDS image and fragment reads are identical to the verified VGPR version.
// ---------------------------------------------------------------------------
__global__ __launch_bounds__(256) void k_gemm_bt(
    const short* __restrict__ A, const short* __restrict__ B,
    float* __restrict__ Cf, short* __restrict__ Cb,
    const float* __restrict__ bias,
    int M, int N, int K, int lda, int ldb, int ldc,
    int z0n, long sA0, long sA1, long sB0, long sB1, long sC0, long sC1,
    int act, int gap)
{
    __shared__ __align__(16) short lds[2 * 128 * 32];
    const int z = blockIdx.z;
    const int z0 = z % z0n, z1 = z / z0n;
    A += z1 * sA1 + z0 * sA0;
    B += z1 * sB1 + z0 * sB0;
    const long coff = z1 * sC1 + z0 * sC0;
    const int tn0 = blockIdx.x * 128, tm0 = blockIdx.y * 128;
    const int tid = threadIdx.x, ln = tid & 63, wv = tid >> 6;
    const int wr = wv >> 1, wc = wv & 1;

    // per-lane global base for this wave's 4 staging calls; slot = c*64 + ln
    // slot p holds global chunk (row = p>>2, col = (p&3)^((p>>3)&3))
    const short* gbase[4];
    {
        const int gcol = (ln & 3) ^ ((ln >> 3) & 3);
#pragma unroll
        for (int j = 0; j < 4; ++j) {
            int c = wv * 4 + j;
            if (c < 8) {
                long grow = (long)(tm0 + c * 16 + (ln >> 2));
                if (gap) grow += 2 * (grow >> 10);
                gbase[j] = A + grow * (long)lda + gcol * 8;
            } else {
                gbase[j] = B + (long)(tn0 + (c - 8) * 16 + (ln >> 2)) * ldb + gcol * 8;
            }
        }
    }

    float4v acc[4][4];
#pragma unroll
    for (int i = 0; i < 4; ++i)
#pragma unroll
        for (int j = 0; j < 4; ++j) acc[i][j] = (float4v){0.f, 0.f, 0.f, 0.f};

    const int nk = K >> 5;
    for (int kt = 0; kt < nk; ++kt) {
        __syncthreads();
#pragma unroll
        for (int j = 0; j < 4; ++j) {
            int c = wv * 4 + j;
            __builtin_amdgcn_global_load_lds(
                (const __attribute__((address_space(1))) void*)(gbase[j] + kt * 32),
                (__attribute__((address_space(3))) void*)((short8*)lds + c * 64),
                16, 0, 0);
        }
        __syncthreads();   // vmcnt(0) drain: staged data visible

        short8 af[4], bf_[4];
        const int q = ln >> 4;
#pragma unroll
        for (int i = 0; i < 4; ++i) {
            int r = wr * 64 + i * 16 + (ln & 15);
            af[i] = ((short8*)lds)[r * 4 + (q ^ ((r >> 1) & 3))];
        }
#pragma unroll
        for (int j = 0; j < 4; ++j) {
            int r = wc * 64 + j * 16 + (ln & 15);
            bf_[j] = ((short8*)lds)[512 + r * 4 + (q ^ ((r >> 1) & 3))];
        }
#pragma unroll
        for (int i = 0; i < 4; ++i)
#pragma unroll
            for (int j = 0; j < 4; ++j)
                acc[i][j] = __builtin_amdgcn_mfma_f32_16x16x32_bf16(af[i], bf_[j], acc[i][j], 0, 0, 0);
    }

#pragma unroll
    for (int j = 0; j < 4; ++j) {
        int nglob = tn0 + wc * 64 + j * 16 + (ln & 15);
        float bv = bias ? bias[nglob] : 0.f;
#pragma unroll
        for (int i = 0; i < 4; ++i) {
#pragma unroll
            for (int r = 0; r < 4; ++r) {
                int mglob = tm0 + wr * 64 + i * 16 + (ln >> 4) * 4 + r;
                float v = acc[i][j][r] + bv;
                if (act == 1) v = (v >= 0.f) ? v : 0.25f * v;
                else if (act == 2) v = fmaxf(v, 0.f);
                long ci = coff + (long)mglob * ldc + nglob;
                if (Cf) Cf[ci] = v;
                if (Cb) Cb[ci] = f2b(v);
            }
        }
    }
}

// ---------------------------------------------------------------------------
// Row softmax over 1024, bf16 in-place
// ---------------------------------------------------------------------------
__global__ __launch_bounds__(256) void k_softmax_rows_bf16(short* __restrict__ p) {
    long row = blockIdx.x;
    short* r = p + (row << 10);
    int tid = threadIdx.x;
    float v[4];
    float mx = -3.4e38f;
#pragma unroll
    for (int i = 0; i < 4; ++i) { v[i] = b2f(r[tid + (i << 8)]); mx = fmaxf(mx, v[i]); }
#pragma unroll
    for (int d = 32; d > 0; d >>= 1) mx = fmaxf(mx, __shfl_down(mx, d));
    __shared__ float red[4], red2[4];
    if ((tid & 63) == 0) red[tid >> 6] = mx;
    __syncthreads();
    mx = fmaxf(fmaxf(red[0], red[1]), fmaxf(red[2], red[3]));
    float s = 0.f;
#pragma unroll
    for (int i = 0; i < 4; ++i) { v[i] = expf(v[i] - mx); s += v[i]; }
#pragma unroll
    for (int d = 32; d > 0; d >>= 1) s += __shfl_down(s, d);
    if ((tid & 63) == 0) red2[tid >> 6] = s;
    __syncthreads();
    s = red2[0] + red2[1] + red2[2] + red2[3];
    float inv = 1.f / s;
#pragma unroll
    for (int i = 0; i < 4; ++i) r[tid + (i << 8)] = f2b(v[i] * inv);
}

// fp32 softmax over T=1024, in place
__global__ __launch_bounds__(256) void k_softmax_rows_f32(float* __restrict__ p) {
    long row = blockIdx.x;
    float* r = p + (row << 10);
    int tid = threadIdx.x;
    float v[4];
    float mx = -3.4e38f;
#pragma unroll
    for (int i = 0; i < 4; ++i) { v[i] = r[tid + (i << 8)]; mx = fmaxf(mx, v[i]); }
#pragma unroll
    for (int d = 32; d > 0; d >>= 1) mx = fmaxf(mx, __shfl_down(mx, d));
    __shared__ float red[4], red2[4];
    if ((tid & 63) == 0) red[tid >> 6] = mx;
    __syncthreads();
    mx = fmaxf(fmaxf(red[0], red[1]), fmaxf(red[2], red[3]));
    float s = 0.f;
#pragma unroll
    for (int i = 0; i < 4; ++i) { v[i] = expf(v[i] - mx); s += v[i]; }
#pragma unroll
    for (int d = 32; d > 0; d >>= 1) s += __shfl_down(s, d);
    if ((tid & 63) == 0) red2[tid >> 6] = s;
    __syncthreads();
    s = red2[0] + red2[1] + red2[2] + red2[3];
    float inv = 1.f / s;
#pragma unroll
    for (int i = 0; i < 4; ++i) r[tid + (i << 8)] = v[i] * inv;
}

// ---------------------------------------------------------------------------
// LayerNorm over E=512 (bf16 in -> bf16 out), rows = 8192
// ---------------------------------------------------------------------------
__global__ __launch_bounds__(256) void k_layernorm(const short* __restrict__ y,
                                                   const float* __restrict__ gam,
                                                   const float* __restrict__ bet,
                                                   short* __restrict__ o) {
    const long row = blockIdx.x;
    const short* r = y + (row << 9);
    const int tid = threadIdx.x;
    float v0 = b2f(r[tid]), v1 = b2f(r[tid + 256]);
    float s = v0 + v1, ss = v0 * v0 + v1 * v1;
#pragma unroll
    for (int d = 32; d > 0; d >>= 1) { s += __shfl_down(s, d); ss += __shfl_down(ss, d); }
    __shared__ float rs_[4], rss[4];
    if ((tid & 63) == 0) { rs_[tid >> 6] = s; rss[tid >> 6] = ss; }
    __syncthreads();
    s = rs_[0] + rs_[1] + rs_[2] + rs_[3];
    ss = rss[0] + rss[1] + rss[2] + rss[3];
    float mean = s * (1.f / 512.f);
    float var = ss * (1.f / 512.f) - mean * mean;
    float rstd = rsqrtf(var + 1e-5f);
    short* out = o + (row << 9);
    out[tid]       = f2b((v0 - mean) * rstd * gam[tid]       + bet[tid]);
    out[tid + 256] = f2b((v1 - mean) * rstd * gam[tid + 256] + bet[tid + 256]);
}

// ---------------------------------------------------------------------------
// v [8192][2048] -> vT [32][512][1024] ([bn][d][s])
// ---------------------------------------------------------------------------
__global__ __launch_bounds__(256) void k_vT(const short* __restrict__ v, short* __restrict__ vT) {
    __shared__ short t[32][34];
    int bn = blockIdx.z, b = bn >> 2, n = bn & 3;
    int s0 = blockIdx.y * 32, d0 = blockIdx.x * 32;
    int lx = threadIdx.x & 31, ly = threadIdx.x >> 5;
#pragma unroll
    for (int i = 0; i < 4; ++i) {
        int s = ly + i * 8;
        t[s][lx] = v[(long)(b * 1024 + s0 + s) * 2048 + n * 512 + d0 + lx];
    }
    __syncthreads();
#pragma unroll
    for (int i = 0; i < 4; ++i) {
        int d = ly + i * 8;
        vT[((long)bn * 512 + d0 + d) * 1024 + s0 + lx] = t[lx][d];
    }
}

// ---------------------------------------------------------------------------
// Persistent LSTM — 64 blocks, split-flag protocol:
//  * waves 0,1 compute gates (8 batches x 16 units), store h, then each
//    does its OWN s_waitcnt vmcnt(0) and raises its OWN flag
//    (arr[g] / arr[64+g]) — drain covers only that wave's h stores.
//  * lpad store + ig prefetch AFTER the flag (off the critical path).
//  * wave0 polls both 64-flag arrays (2 loads — round-3-proven volume);
//    trailing __syncthreads releases the block. 2 syncs/step.
// ---------------------------------------------------------------------------
__global__ __launch_bounds__(256) void k_lstm(
    const short* __restrict__ whh, const short* __restrict__ igb,
    short* __restrict__ hA, short* __restrict__ hB,
    short* __restrict__ lstm_pad, int* __restrict__ arr)
{
    const int g = blockIdx.x;            // 0..63, owns units g*16..g*16+15
    const int tid = threadIdx.x;
    const int ln = tid & 63, wv = tid >> 6;
    const int kbase = wv * 256 + ((ln >> 4) << 3);
    const int arow = ln & 15;            // batch rows; 8..15 stay zero

    // wf[q][kk]: B-frag for gate q's 16 units, this wave's K-quarter
    short8 wf[4][8];
#pragma unroll
    for (int q = 0; q < 4; ++q) {
        long row = (long)q * 1024 + g * 16 + (ln & 15);
#pragma unroll
        for (int kk = 0; kk < 8; ++kk)
            wf[q][kk] = *(const short8*)&whh[row * 1024 + kbase + kk * 32];
    }

    __shared__ float part[4][16][68];
    const int gm = tid >> 4, gu = tid & 15;   // gate threads tid<128: batch, unit
    float c_prev = 0.f;
    float igv[4];
    if (tid < 128) {
#pragma unroll
        for (int q = 0; q < 4; ++q)
            igv[q] = b2f(igb[((long)gm * 1024 + 0) * 4096 + q * 1024 + g * 16 + gu]);
    }

    for (int step = 0; step < 1024; ++step) {
        // ---- h fragment load (relaxed agent atomics = plain sc0 sc1) ----
        const short* hp = (step & 1) ? hB : hA;
        short8 af[8];
        if (arow < 8) {
            const unsigned long long* hq =
                (const unsigned long long*)(hp + arow * 1024 + kbase);
#pragma unroll
            for (int kk = 0; kk < 8; ++kk) {
                union { unsigned long long u[2]; short8 s; } cv;
                cv.u[0] = __hip_atomic_load(hq + kk * 8,     __ATOMIC_RELAXED, __HIP_MEMORY_SCOPE_AGENT);
                cv.u[1] = __hip_atomic_load(hq + kk * 8 + 1, __ATOMIC_RELAXED, __HIP_MEMORY_SCOPE_AGENT);
                af[kk] = cv.s;
            }
        } else {
#pragma unroll
            for (int kk = 0; kk < 8; ++kk) af[kk] = (short8){0, 0, 0, 0, 0, 0, 0, 0};
        }

        float4v acc[4];
#pragma unroll
        for (int q = 0; q < 4; ++q) acc[q] = (float4v){0.f, 0.f, 0.f, 0.f};
#pragma unroll
        for (int kk = 0; kk < 8; ++kk)
#pragma unroll
            for (int q = 0; q < 4; ++q)
                acc[q] = __builtin_amdgcn_mfma_f32_16x16x32_bf16(af[kk], wf[q][kk], acc[q], 0, 0, 0);

        // prev-step readers finished before prev trailing sync -> safe write
#pragma unroll
        for (int q = 0; q < 4; ++q)
#pragma unroll
            for (int rr = 0; rr < 4; ++rr)
                part[wv][(ln >> 4) * 4 + rr][q * 16 + (ln & 15)] = acc[q][rr];
        __syncthreads();

        short hb16 = 0;
        if (tid < 128) {
            float psum[4];
#pragma unroll
            for (int q = 0; q < 4; ++q)
                psum[q] = part[0][gm][q * 16 + gu] + part[1][gm][q * 16 + gu]
                        + part[2][gm][q * 16 + gu] + part[3][gm][q * 16 + gu];
            float g0 = psum[0] + igv[0];
            float g1 = psum[1] + igv[1];
            float g2 = psum[2] + igv[2];
            float g3 = psum[3] + igv[3];
            float iv = 1.f / (1.f + __expf(-g0));
            float fv = 1.f / (1.f + __expf(-g1));
            float gv = 2.f / (1.f + __expf(-2.f * g2)) - 1.f;
            float ov = 1.f / (1.f + __expf(-g3));
            float c = fv * c_prev + iv * gv;
            c_prev = c;
            float h = ov * (2.f / (1.f + __expf(-2.f * c)) - 1.f);
            hb16 = f2b(h);
            short* hn = (step & 1) ? hA : hB;
            __hip_atomic_store(&hn[gm * 1024 + g * 16 + gu], hb16,
                               __ATOMIC_RELAXED, __HIP_MEMORY_SCOPE_AGENT);
        }
        if (wv < 2) {
            // drain THIS wave's h stores, then raise this wave's flag
            asm volatile("s_waitcnt vmcnt(0)" ::: "memory");
            if ((tid & 63) == 0)
                __hip_atomic_store(&arr[(wv << 6) + g], step + 1,
                                   __ATOMIC_RELAXED, __HIP_MEMORY_SCOPE_AGENT);
        }
        if (tid < 128) {
            lstm_pad[((long)gm * 1026 + step + 1) * 1024 + g * 16 + gu] = hb16;
            if (step + 1 < 1024) {
#pragma unroll
                for (int q = 0; q < 4; ++q)
                    igv[q] = b2f(igb[((long)gm * 1024 + step + 1) * 4096 + q * 1024 + g * 16 + gu]);
            }
        }
        if (wv == 0) {
            const int target = step + 1;
            long att = 0;
            while (true) {
                int f0 = __hip_atomic_load(&arr[ln],      __ATOMIC_RELAXED, __HIP_MEMORY_SCOPE_AGENT);
                int f1 = __hip_atomic_load(&arr[64 + ln], __ATOMIC_RELAXED, __HIP_MEMORY_SCOPE_AGENT);
                if (__all(f0 >= target && f1 >= target)) break;
                if (++att > 20000000L) break;   // never hang
                __builtin_amdgcn_s_sleep(1);
            }
        }
        __syncthreads();
    }
}

// ---------------------------------------------------------------------------
// conv2: a1 [8192][512] bf16 (relu'd), w [2][512][3] staged in LDS,
// short8-vectorized A loads. grid 64: blk = b*8 + c*4 + quarter.
// ---------------------------------------------------------------------------
__global__ __launch_bounds__(256) void k_conv2(const short* __restrict__ a1,
                                               const float* __restrict__ w,
                                               const float* __restrict__ bias,
                                               float* __restrict__ a2) {
    __shared__ float wl[1536];
    int blk = blockIdx.x;
    int b = blk >> 3, c = (blk >> 2) & 1, t0 = (blk & 3) * 256;
    int tid = threadIdx.x;
    for (int i = tid; i < 1536; i += 256) wl[i] = w[c * 1536 + i];
    __syncthreads();
    int t = t0 + tid;
    float s = bias[c];
    for (int dk = 0; dk < 3; ++dk) {
        int tt = t + dk - 1;
        if (tt < 0 || tt >= 1024) continue;
        const short8* arow = (const short8*)(a1 + (long)(b * 1024 + tt) * 512);
        for (int j = 0; j < 64; ++j) {
            short8 v = arow[j];
#pragma unroll
            for (int u = 0; u < 8; ++u)
                s += b2f(v[u]) * wl[(j * 8 + u) * 3 + dk];
        }
    }
    a2[(b * 2 + c) * 1024 + t] = s;
}

// ---------------------------------------------------------------------------
// feat[b][c][h] = sum_t attw[(b*2+c)*1024+t] * lstm_pad[b][t+1][h]
// grid 64: blk = bc*4 + h-quarter.
// ---------------------------------------------------------------------------
__global__ __launch_bounds__(256) void k_feat(const float* __restrict__ attw,
                                              const short* __restrict__ lstm_pad,
                                              float* __restrict__ out) {
    int blk = blockIdx.x;
    int bc = blk >> 2, qh = blk & 3;
    int b = bc >> 1;
    int tid = threadIdx.x;
    int h = qh * 256 + tid;
    __shared__ float aw[1024];
    for (int i = tid; i < 1024; i += 256) aw[i] = attw[bc * 1024 + i];
    __syncthreads();
    float acc = 0.f;
#pragma unroll 4
    for (int t = 0; t < 1024; ++t)
        acc += aw[t] * b2f(lstm_pad[((long)(b * 1026 + t + 1)) * 1024 + h]);
    out[bc * 1024 + h] = acc;
}

// ---------------------------------------------------------------------------
// Host orchestration
// ---------------------------------------------------------------------------
static void gemm_bt(hipStream_t st, const short* A, const short* B, float* Cf, short* Cb,
                    const float* bias, int M, int N, int K, int lda, int ldb, int ldc,
                    int z, int z0n, long sA0, long sA1, long sB0, long sB1, long sC0, long sC1,
                    int act, int gap) {
    dim3 grid(N / 128, M / 128, z);
    k_gemm_bt<<<grid, dim3(256), 0, st>>>(A, B, Cf, Cb, bias, M, N, K, lda, ldb, ldc,
                                          z0n, sA0, sA1, sB0, sB1, sC0, sC1, act, gap);
}

extern "C" void kernel_launch(void* const* d_in, const int* in_sizes, int n_in,
                              void* d_out, int out_size, void* d_ws, size_t ws_size,
                              hipStream_t stream) {
    if (ws_size < 199409920u) return;

    const float* x     = (const float*)d_in[0];
    const float* w_in1 = (const float*)d_in[1];
    const float* b_in1 = (const float*)d_in[2];
    const float* w_in2 = (const float*)d_in[3];
    const float* b_in2 = (const float*)d_in[4];
    const float* w_q   = (const float*)d_in[5];
    const float* b_q   = (const float*)d_in[6];
    const float* w_k   = (const float*)d_in[7];
    const float* b_k   = (const float*)d_in[8];
    const float* w_v   = (const float*)d_in[9];
    const float* b_v   = (const float*)d_in[10];
    const float* w_p   = (const float*)d_in[11];
    const float* b_p   = (const float*)d_in[12];
    const float* ln_g  = (const float*)d_in[13];
    const float* ln_b  = (const float*)d_in[14];
    const float* w_ih  = (const float*)d_in[15];
    const float* w_hh  = (const float*)d_in[16];
    const float* b_ih  = (const float*)d_in[17];
    const float* b_hh  = (const float*)d_in[18];
    const float* w_c1  = (const float*)d_in[19];
    const float* b_c1  = (const float*)d_in[20];
    const float* w_c2  = (const float*)d_in[21];
    const float* b_c2  = (const float*)d_in[22];

    char* ws = (char*)d_ws;
    // ---- static region ----
    short* w1b  = (short*)(ws + 0);
    short* w2b  = (short*)(ws + 524288);
    short* wqb  = (short*)(ws + 1048576);
    short* wkb  = (short*)(ws + 2097152);
    short* wvb  = (short*)(ws + 3145728);
    short* wpb  = (short*)(ws + 5242880);
    short* wihb = (short*)(ws + 7340032);
    short* whhb = (short*)(ws + 11534336);
    short* wc1b = (short*)(ws + 19922944);
    float* bsum = (float*)(ws + 23068672);
    short* hs0  = (short*)(ws + 23085056);     // 32 KB
    short* hs1  = (short*)(ws + 23117824);     // 32 KB
    int*   arr  = (int*)  (ws + 23150592);     // 512 B
    float* a2   = (float*)(ws + 23150848);
    short* lpad = (short*)(ws + 23216384);
    // ---- dynamic region D0 = 40,026,368 ----
    const size_t D0 = 40026368u;
    short* xbf   = (short*)(ws + D0);
    short* h1bf  = (short*)(ws + D0 + 8388608);
    short* h2bf  = (short*)(ws + D0 + 16777216);
    short* qbf   = (short*)(ws + D0 + 25165824);
    short* kbf   = (short*)(ws + D0 + 41943040);
    short* vbf   = (short*)(ws + D0 + 58720256);
    short* vTbf  = (short*)(ws + D0 + 92274688);
    short* scb   = (short*)(ws + D0);
    short* obf   = (short*)(ws + D0 + 125829120);
    short* ybf   = (short*)(ws + D0 + 58720256);
    short* ylnbf = (short*)(ws + D0 + 67108864);
    short* igb   = (short*)(ws + D0 + 92274688);
    short* a1bf  = (short*)(ws + D0);

    hipMemsetAsync(lpad, 0, (size_t)8 * 1026 * 1024 * 2, stream);
    hipMemsetAsync(hs0, 0, 32768, stream);
    hipMemsetAsync(hs1, 0, 32768, stream);
    hipMemsetAsync(arr, 0, 512, stream);

    k_f32_to_bf16<<<dim3(4096), dim3(256), 0, stream>>>(x, xbf, 8192 * 512);
    k_cvt_weights<<<dim3(4096), dim3(256), 0, stream>>>(w_in1, w_in2, w_q, w_k, w_v, w_p,
                                                        w_ih, w_hh, w1b);
    k_wc1_tr<<<dim3((512 * 3072 + 255) / 256), dim3(256), 0, stream>>>(w_c1, wc1b);
    k_bias_sum<<<dim3(16), dim3(256), 0, stream>>>(b_ih, b_hh, bsum, 4096);

    gemm_bt(stream, xbf, w1b, nullptr, h1bf, b_in1, 8192, 512, 512, 512, 512, 512,
            1, 1, 0, 0, 0, 0, 0, 0, 1, 0);
    gemm_bt(stream, h1bf, w2b, nullptr, h2bf, b_in2, 8192, 512, 512, 512, 512, 512,
            1, 1, 0, 0, 0, 0, 0, 0, 0, 0);
    gemm_bt(stream, h2bf, wqb, nullptr, qbf, b_q, 8192, 1024, 512, 512, 512, 1024,
            1, 1, 0, 0, 0, 0, 0, 0, 0, 0);
    gemm_bt(stream, h2bf, wkb, nullptr, kbf, b_k, 8192, 1024, 512, 512, 512, 1024,
            1, 1, 0, 0, 0, 0, 0, 0, 0, 0);
    gemm_bt(stream, h2bf, wvb, nullptr, vbf, b_v, 8192, 2048, 512, 512, 512, 2048,
            1, 1, 0, 0, 0, 0, 0, 0, 0, 0);
    k_vT<<<dim3(16, 32, 32), dim3(256), 0, stream>>>(vbf, vTbf);

    for (int bg = 0; bg < 4; ++bg) {
        const short* qb = qbf + (long)bg * 2097152;
        const short* kb = kbf + (long)bg * 2097152;
        gemm_bt(stream, qb, kb, nullptr, scb, nullptr, 1024, 1024, 256, 1024, 1024, 1024,
                8, 4, 256, 1048576, 256, 1048576, 1048576, 4194304, 0, 0);
        k_softmax_rows_bf16<<<dim3(8192), dim3(256), 0, stream>>>(scb);
        gemm_bt(stream, scb, vTbf + (long)bg * 4194304, nullptr, obf + (long)bg * 4194304, nullptr,
                1024, 512, 1024, 1024, 1024, 2048,
                8, 4, 1048576, 4194304, 524288, 2097152, 512, 2097152, 0, 0);
    }

    gemm_bt(stream, obf, wpb, nullptr, ybf, b_p, 8192, 512, 2048, 2048, 2048, 512,
            1, 1, 0, 0, 0, 0, 0, 0, 0, 0);
    k_layernorm<<<dim3(8192), dim3(256), 0, stream>>>(ybf, ln_g, ln_b, ylnbf);
    gemm_bt(stream, ylnbf, wihb, nullptr, igb, bsum, 8192, 4096, 512, 512, 512, 4096,
            1, 1, 0, 0, 0, 0, 0, 0, 0, 0);
    k_lstm<<<dim3(64), dim3(256), 0, stream>>>(whhb, igb, hs0, hs1, lpad, arr);
    gemm_bt(stream, lpad, wc1b, nullptr, a1bf, b_c1, 8192, 512, 3072, 1024, 3072, 512,
            1, 1, 0, 0, 0, 0, 0, 0, 2, 1);
    k_conv2<<<dim3(64), dim3(256), 0, stream>>>(a1bf, w_c2, b_c2, a2);
    k_softmax_rows_f32<<<dim3(16), dim3(256), 0, stream>>>(a2);
    k_feat<<<dim3(64), dim3(256), 0, stream>>>(a2, lpad, (float*)d_out);
    (void)in_sizes; (void)n_in; (void)out_size; (void)ws_size;
}

// Round 10
// 4089.399 us; speedup vs baseline: 1.1419x; 1.1419x over previous
//
#include <hip/hip_runtime.h>
#include <stdint.h>

// ---------------------------------------------------------------------------
// Types / helpers
// ---------------------------------------------------------------------------
typedef short short8 __attribute__((ext_vector_type(8)));
typedef short short4v __attribute__((ext_vector_type(4)));
typedef float float4v __attribute__((ext_vector_type(4)));

__device__ __forceinline__ float b2f(short s) {
    return __uint_as_float(((unsigned)(unsigned short)s) << 16);
}
__device__ __forceinline__ short f2b(float f) {
    unsigned u = __float_as_uint(f);
    unsigned r = (u + 0x7fffu + ((u >> 16) & 1u)) >> 16;
    return (short)r;
}

// ---------------------------------------------------------------------------
// fp32 -> bf16 convert, float4-vectorized (n divisible by 4)
// ---------------------------------------------------------------------------
__global__ void k_f32_to_bf16(const float4v* __restrict__ in, short4v* __restrict__ out, int n4) {
    int i = blockIdx.x * blockDim.x + threadIdx.x;
    int stride = gridDim.x * blockDim.x;
    for (; i < n4; i += stride) {
        float4v v = in[i];
        short4v o;
        o[0] = f2b(v[0]); o[1] = f2b(v[1]); o[2] = f2b(v[2]); o[3] = f2b(v[3]);
        out[i] = o;
    }
}

// Fused converter for the 8 contiguous weight buffers (quad indices)
__global__ void k_cvt_weights(const float4v* __restrict__ s0, const float4v* __restrict__ s1,
                              const float4v* __restrict__ s2, const float4v* __restrict__ s3,
                              const float4v* __restrict__ s4, const float4v* __restrict__ s5,
                              const float4v* __restrict__ s6, const float4v* __restrict__ s7,
                              short4v* __restrict__ dst) {
    int i = blockIdx.x * blockDim.x + threadIdx.x;
    int stride = gridDim.x * blockDim.x;
    for (; i < 2490368; i += stride) {
        float4v v;
        if      (i <   65536) v = s0[i];
        else if (i <  131072) v = s1[i -   65536];
        else if (i <  262144) v = s2[i -  131072];
        else if (i <  393216) v = s3[i -  262144];
        else if (i <  655360) v = s4[i -  393216];
        else if (i <  917504) v = s5[i -  655360];
        else if (i < 1441792) v = s6[i -  917504];
        else                  v = s7[i - 1441792];
        short4v o;
        o[0] = f2b(v[0]); o[1] = f2b(v[1]); o[2] = f2b(v[2]); o[3] = f2b(v[3]);
        dst[i] = o;
    }
}

// w_c1 [512][1024][3] -> bf16 [512][3*1024]
__global__ void k_wc1_tr(const float* __restrict__ in, short* __restrict__ out) {
    int i = blockIdx.x * blockDim.x + threadIdx.x;
    if (i >= 512 * 3072) return;
    int c = i / 3072, rr = i % 3072, dk = rr / 1024, h = rr % 1024;
    out[i] = f2b(in[(c * 1024 + h) * 3 + dk]);
}

__global__ void k_bias_sum(const float* __restrict__ a, const float* __restrict__ b,
                           float* __restrict__ o, int n) {
    int i = blockIdx.x * blockDim.x + threadIdx.x;
    if (i < n) o[i] = a[i] + b[i];
}

// ---------------------------------------------------------------------------
// Generic batched GEMM:  C[m][n] = act( sum_k A[m][k]*B[n][k] + bias[n] )
// Staging via global_load_lds width=16; XOR swizzle applied source-side.
// ---------------------------------------------------------------------------
__global__ __launch_bounds__(256) void k_gemm_bt(
    const short* __restrict__ A, const short* __restrict__ B,
    float* __restrict__ Cf, short* __restrict__ Cb,
    const float* __restrict__ bias,
    int M, int N, int K, int lda, int ldb, int ldc,
    int z0n, long sA0, long sA1, long sB0, long sB1, long sC0, long sC1,
    int act, int gap)
{
    __shared__ __align__(16) short lds[2 * 128 * 32];
    const int z = blockIdx.z;
    const int z0 = z % z0n, z1 = z / z0n;
    A += z1 * sA1 + z0 * sA0;
    B += z1 * sB1 + z0 * sB0;
    const long coff = z1 * sC1 + z0 * sC0;
    const int tn0 = blockIdx.x * 128, tm0 = blockIdx.y * 128;
    const int tid = threadIdx.x, ln = tid & 63, wv = tid >> 6;
    const int wr = wv >> 1, wc = wv & 1;

    // per-lane global base for this wave's 4 staging calls; slot = c*64 + ln
    const short* gbase[4];
    {
        const int gcol = (ln & 3) ^ ((ln >> 3) & 3);
#pragma unroll
        for (int j = 0; j < 4; ++j) {
            int c = wv * 4 + j;
            if (c < 8) {
                long grow = (long)(tm0 + c * 16 + (ln >> 2));
                if (gap) grow += 2 * (grow >> 10);
                gbase[j] = A + grow * (long)lda + gcol * 8;
            } else {
                gbase[j] = B + (long)(tn0 + (c - 8) * 16 + (ln >> 2)) * ldb + gcol * 8;
            }
        }
    }

    float4v acc[4][4];
#pragma unroll
    for (int i = 0; i < 4; ++i)
#pragma unroll
        for (int j = 0; j < 4; ++j) acc[i][j] = (float4v){0.f, 0.f, 0.f, 0.f};

    const int nk = K >> 5;
    for (int kt = 0; kt < nk; ++kt) {
        __syncthreads();
#pragma unroll
        for (int j = 0; j < 4; ++j) {
            int c = wv * 4 + j;
            __builtin_amdgcn_global_load_lds(
                (const __attribute__((address_space(1))) void*)(gbase[j] + kt * 32),
                (__attribute__((address_space(3))) void*)((short8*)lds + c * 64),
                16, 0, 0);
        }
        __syncthreads();

        short8 af[4], bf_[4];
        const int q = ln >> 4;
#pragma unroll
        for (int i = 0; i < 4; ++i) {
            int r = wr * 64 + i * 16 + (ln & 15);
            af[i] = ((short8*)lds)[r * 4 + (q ^ ((r >> 1) & 3))];
        }
#pragma unroll
        for (int j = 0; j < 4; ++j) {
            int r = wc * 64 + j * 16 + (ln & 15);
            bf_[j] = ((short8*)lds)[512 + r * 4 + (q ^ ((r >> 1) & 3))];
        }
#pragma unroll
        for (int i = 0; i < 4; ++i)
#pragma unroll
            for (int j = 0; j < 4; ++j)
                acc[i][j] = __builtin_amdgcn_mfma_f32_16x16x32_bf16(af[i], bf_[j], acc[i][j], 0, 0, 0);
    }

#pragma unroll
    for (int j = 0; j < 4; ++j) {
        int nglob = tn0 + wc * 64 + j * 16 + (ln & 15);
        float bv = bias ? bias[nglob] : 0.f;
#pragma unroll
        for (int i = 0; i < 4; ++i) {
#pragma unroll
            for (int r = 0; r < 4; ++r) {
                int mglob = tm0 + wr * 64 + i * 16 + (ln >> 4) * 4 + r;
                float v = acc[i][j][r] + bv;
                if (act == 1) v = (v >= 0.f) ? v : 0.25f * v;
                else if (act == 2) v = fmaxf(v, 0.f);
                long ci = coff + (long)mglob * ldc + nglob;
                if (Cf) Cf[ci] = v;
                if (Cb) Cb[ci] = f2b(v);
            }
        }
    }
}

// ---------------------------------------------------------------------------
// Row softmax over 1024, bf16 in-place
// ---------------------------------------------------------------------------
__global__ __launch_bounds__(256) void k_softmax_rows_bf16(short* __restrict__ p) {
    long row = blockIdx.x;
    short* r = p + (row << 10);
    int tid = threadIdx.x;
    float v[4];
    float mx = -3.4e38f;
#pragma unroll
    for (int i = 0; i < 4; ++i) { v[i] = b2f(r[tid + (i << 8)]); mx = fmaxf(mx, v[i]); }
#pragma unroll
    for (int d = 32; d > 0; d >>= 1) mx = fmaxf(mx, __shfl_down(mx, d));
    __shared__ float red[4], red2[4];
    if ((tid & 63) == 0) red[tid >> 6] = mx;
    __syncthreads();
    mx = fmaxf(fmaxf(red[0], red[1]), fmaxf(red[2], red[3]));
    float s = 0.f;
#pragma unroll
    for (int i = 0; i < 4; ++i) { v[i] = expf(v[i] - mx); s += v[i]; }
#pragma unroll
    for (int d = 32; d > 0; d >>= 1) s += __shfl_down(s, d);
    if ((tid & 63) == 0) red2[tid >> 6] = s;
    __syncthreads();
    s = red2[0] + red2[1] + red2[2] + red2[3];
    float inv = 1.f / s;
#pragma unroll
    for (int i = 0; i < 4; ++i) r[tid + (i << 8)] = f2b(v[i] * inv);
}

// ---------------------------------------------------------------------------
// LayerNorm over E=512 (bf16 in -> bf16 out), rows = 8192
// ---------------------------------------------------------------------------
__global__ __launch_bounds__(256) void k_layernorm(const short* __restrict__ y,
                                                   const float* __restrict__ gam,
                                                   const float* __restrict__ bet,
                                                   short* __restrict__ o) {
    const long row = blockIdx.x;
    const short* r = y + (row << 9);
    const int tid = threadIdx.x;
    float v0 = b2f(r[tid]), v1 = b2f(r[tid + 256]);
    float s = v0 + v1, ss = v0 * v0 + v1 * v1;
#pragma unroll
    for (int d = 32; d > 0; d >>= 1) { s += __shfl_down(s, d); ss += __shfl_down(ss, d); }
    __shared__ float rs_[4], rss[4];
    if ((tid & 63) == 0) { rs_[tid >> 6] = s; rss[tid >> 6] = ss; }
    __syncthreads();
    s = rs_[0] + rs_[1] + rs_[2] + rs_[3];
    ss = rss[0] + rss[1] + rss[2] + rss[3];
    float mean = s * (1.f / 512.f);
    float var = ss * (1.f / 512.f) - mean * mean;
    float rstd = rsqrtf(var + 1e-5f);
    short* out = o + (row << 9);
    out[tid]       = f2b((v0 - mean) * rstd * gam[tid]       + bet[tid]);
    out[tid + 256] = f2b((v1 - mean) * rstd * gam[tid + 256] + bet[tid + 256]);
}

// ---------------------------------------------------------------------------
// v [8192][2048] -> vT [32][512][1024] ([bn][d][s])
// ---------------------------------------------------------------------------
__global__ __launch_bounds__(256) void k_vT(const short* __restrict__ v, short* __restrict__ vT) {
    __shared__ short t[32][34];
    int bn = blockIdx.z, b = bn >> 2, n = bn & 3;
    int s0 = blockIdx.y * 32, d0 = blockIdx.x * 32;
    int lx = threadIdx.x & 31, ly = threadIdx.x >> 5;
#pragma unroll
    for (int i = 0; i < 4; ++i) {
        int s = ly + i * 8;
        t[s][lx] = v[(long)(b * 1024 + s0 + s) * 2048 + n * 512 + d0 + lx];
    }
    __syncthreads();
#pragma unroll
    for (int i = 0; i < 4; ++i) {
        int d = ly + i * 8;
        vT[((long)bn * 512 + d0 + d) * 1024 + s0 + lx] = t[lx][d];
    }
}

// ---------------------------------------------------------------------------
// Persistent LSTM — round-8 protocol verbatim (best measured: 3.29 ms):
// 64 blocks x 16 h-units, wave0-only flag poll, 3 syncs/step,
// relaxed agent atomics, block-wide drain via __syncthreads before flag.
// ---------------------------------------------------------------------------
__global__ __launch_bounds__(256) void k_lstm(
    const short* __restrict__ whh, const short* __restrict__ igb,
    short* __restrict__ hA, short* __restrict__ hB,
    short* __restrict__ lstm_pad, int* __restrict__ arr)
{
    const int g = blockIdx.x;            // 0..63, owns units g*16..g*16+15
    const int tid = threadIdx.x;
    const int ln = tid & 63, wv = tid >> 6;
    const int kbase = wv * 256 + ((ln >> 4) << 3);
    const int arow = ln & 15;            // batch rows; 8..15 stay zero

    short8 wf[4][8];
#pragma unroll
    for (int q = 0; q < 4; ++q) {
        long row = (long)q * 1024 + g * 16 + (ln & 15);
#pragma unroll
        for (int kk = 0; kk < 8; ++kk)
            wf[q][kk] = *(const short8*)&whh[row * 1024 + kbase + kk * 32];
    }

    __shared__ float part[4][16][68];
    const int gm = tid >> 4, gu = tid & 15;   // gate threads tid<128: batch, unit
    float c_prev = 0.f;
    float igv[4];
    if (tid < 128) {
#pragma unroll
        for (int q = 0; q < 4; ++q)
            igv[q] = b2f(igb[((long)gm * 1024 + 0) * 4096 + q * 1024 + g * 16 + gu]);
    }

    for (int step = 0; step < 1024; ++step) {
        const short* hp = (step & 1) ? hB : hA;
        short8 af[8];
        if (arow < 8) {
            const unsigned long long* hq =
                (const unsigned long long*)(hp + arow * 1024 + kbase);
#pragma unroll
            for (int kk = 0; kk < 8; ++kk) {
                union { unsigned long long u[2]; short8 s; } cv;
                cv.u[0] = __hip_atomic_load(hq + kk * 8,     __ATOMIC_RELAXED, __HIP_MEMORY_SCOPE_AGENT);
                cv.u[1] = __hip_atomic_load(hq + kk * 8 + 1, __ATOMIC_RELAXED, __HIP_MEMORY_SCOPE_AGENT);
                af[kk] = cv.s;
            }
        } else {
#pragma unroll
            for (int kk = 0; kk < 8; ++kk) af[kk] = (short8){0, 0, 0, 0, 0, 0, 0, 0};
        }

        float4v acc[4];
#pragma unroll
        for (int q = 0; q < 4; ++q) acc[q] = (float4v){0.f, 0.f, 0.f, 0.f};
#pragma unroll
        for (int kk = 0; kk < 8; ++kk)
#pragma unroll
            for (int q = 0; q < 4; ++q)
                acc[q] = __builtin_amdgcn_mfma_f32_16x16x32_bf16(af[kk], wf[q][kk], acc[q], 0, 0, 0);

#pragma unroll
        for (int q = 0; q < 4; ++q)
#pragma unroll
            for (int rr = 0; rr < 4; ++rr)
                part[wv][(ln >> 4) * 4 + rr][q * 16 + (ln & 15)] = acc[q][rr];
        __syncthreads();

        if (tid < 128) {
            float psum[4];
#pragma unroll
            for (int q = 0; q < 4; ++q)
                psum[q] = part[0][gm][q * 16 + gu] + part[1][gm][q * 16 + gu]
                        + part[2][gm][q * 16 + gu] + part[3][gm][q * 16 + gu];
            float g0 = psum[0] + igv[0];
            float g1 = psum[1] + igv[1];
            float g2 = psum[2] + igv[2];
            float g3 = psum[3] + igv[3];
            float iv = 1.f / (1.f + __expf(-g0));
            float fv = 1.f / (1.f + __expf(-g1));
            float gv = 2.f / (1.f + __expf(-2.f * g2)) - 1.f;
            float ov = 1.f / (1.f + __expf(-g3));
            float c = fv * c_prev + iv * gv;
            c_prev = c;
            float h = ov * (2.f / (1.f + __expf(-2.f * c)) - 1.f);
            short hb16 = f2b(h);
            short* hn = (step & 1) ? hA : hB;
            __hip_atomic_store(&hn[gm * 1024 + g * 16 + gu], hb16,
                               __ATOMIC_RELAXED, __HIP_MEMORY_SCOPE_AGENT);
            lstm_pad[((long)gm * 1026 + step + 1) * 1024 + g * 16 + gu] = hb16;
        }

        __syncthreads();   // drain: h stores acked before flag
        if (tid == 0)
            __hip_atomic_store(&arr[g], step + 1, __ATOMIC_RELAXED, __HIP_MEMORY_SCOPE_AGENT);
        if (tid < 128 && step + 1 < 1024) {
#pragma unroll
            for (int q = 0; q < 4; ++q)
                igv[q] = b2f(igb[((long)gm * 1024 + step + 1) * 4096 + q * 1024 + g * 16 + gu]);
        }
        if (wv == 0) {
            const int target = step + 1;
            long att = 0;
            while (true) {
                int f0 = __hip_atomic_load(&arr[ln], __ATOMIC_RELAXED, __HIP_MEMORY_SCOPE_AGENT);
                if (__all(f0 >= target)) break;
                if (++att > 20000000L) break;   // never hang
                __builtin_amdgcn_s_sleep(1);
            }
        }
        __syncthreads();
    }
}

// ---------------------------------------------------------------------------
// conv2: a1 [8192][512] bf16 (relu'd), w [2][512][3] staged in LDS.
// ---------------------------------------------------------------------------
__global__ __launch_bounds__(256) void k_conv2(const short* __restrict__ a1,
                                               const float* __restrict__ w,
                                               const float* __restrict__ bias,
                                               float* __restrict__ a2) {
    __shared__ float wl[1536];
    int blk = blockIdx.x;
    int b = blk >> 3, c = (blk >> 2) & 1, t0 = (blk & 3) * 256;
    int tid = threadIdx.x;
    for (int i = tid; i < 1536; i += 256) wl[i] = w[c * 1536 + i];
    __syncthreads();
    int t = t0 + tid;
    float s = bias[c];
    for (int dk = 0; dk < 3; ++dk) {
        int tt = t + dk - 1;
        if (tt < 0 || tt >= 1024) continue;
        const short8* arow = (const short8*)(a1 + (long)(b * 1024 + tt) * 512);
        for (int j = 0; j < 64; ++j) {
            short8 v = arow[j];
#pragma unroll
            for (int u = 0; u < 8; ++u)
                s += b2f(v[u]) * wl[(j * 8 + u) * 3 + dk];
        }
    }
    a2[(b * 2 + c) * 1024 + t] = s;
}

// ---------------------------------------------------------------------------
// feat[b][c][h] = sum_t softmax(a2[bc])[t] * lstm_pad[b][t+1][h]
// softmax over t fused (each block computes its row's softmax redundantly).
// grid 64: blk = bc*4 + h-quarter.
// ---------------------------------------------------------------------------
__global__ __launch_bounds__(256) void k_feat(const float* __restrict__ a2,
                                              const short* __restrict__ lstm_pad,
                                              float* __restrict__ out) {
    int blk = blockIdx.x;
    int bc = blk >> 2, qh = blk & 3;
    int b = bc >> 1;
    int tid = threadIdx.x;
    int h = qh * 256 + tid;
    __shared__ float aw[1024];
    __shared__ float red[4], red2[4];
    float v[4];
    float mx = -3.4e38f;
#pragma unroll
    for (int i = 0; i < 4; ++i) { v[i] = a2[bc * 1024 + tid + (i << 8)]; mx = fmaxf(mx, v[i]); }
#pragma unroll
    for (int d = 32; d > 0; d >>= 1) mx = fmaxf(mx, __shfl_down(mx, d));
    if ((tid & 63) == 0) red[tid >> 6] = mx;
    __syncthreads();
    mx = fmaxf(fmaxf(red[0], red[1]), fmaxf(red[2], red[3]));
    float s = 0.f;
#pragma unroll
    for (int i = 0; i < 4; ++i) { v[i] = __expf(v[i] - mx); s += v[i]; }
#pragma unroll
    for (int d = 32; d > 0; d >>= 1) s += __shfl_down(s, d);
    if ((tid & 63) == 0) red2[tid >> 6] = s;
    __syncthreads();
    s = red2[0] + red2[1] + red2[2] + red2[3];
    float inv = 1.f / s;
#pragma unroll
    for (int i = 0; i < 4; ++i) aw[tid + (i << 8)] = v[i] * inv;
    __syncthreads();
    float acc = 0.f;
#pragma unroll 4
    for (int t = 0; t < 1024; ++t)
        acc += aw[t] * b2f(lstm_pad[((long)(b * 1026 + t + 1)) * 1024 + h]);
    out[bc * 1024 + h] = acc;
}

// ---------------------------------------------------------------------------
// Host orchestration
// ---------------------------------------------------------------------------
static void gemm_bt(hipStream_t st, const short* A, const short* B, float* Cf, short* Cb,
                    const float* bias, int M, int N, int K, int lda, int ldb, int ldc,
                    int z, int z0n, long sA0, long sA1, long sB0, long sB1, long sC0, long sC1,
                    int act, int gap) {
    dim3 grid(N / 128, M / 128, z);
    k_gemm_bt<<<grid, dim3(256), 0, st>>>(A, B, Cf, Cb, bias, M, N, K, lda, ldb, ldc,
                                          z0n, sA0, sA1, sB0, sB1, sC0, sC1, act, gap);
}

extern "C" void kernel_launch(void* const* d_in, const int* in_sizes, int n_in,
                              void* d_out, int out_size, void* d_ws, size_t ws_size,
                              hipStream_t stream) {
    if (ws_size < 199409920u) return;

    const float* x     = (const float*)d_in[0];
    const float* w_in1 = (const float*)d_in[1];
    const float* b_in1 = (const float*)d_in[2];
    const float* w_in2 = (const float*)d_in[3];
    const float* b_in2 = (const float*)d_in[4];
    const float* w_q   = (const float*)d_in[5];
    const float* b_q   = (const float*)d_in[6];
    const float* w_k   = (const float*)d_in[7];
    const float* b_k   = (const float*)d_in[8];
    const float* w_v   = (const float*)d_in[9];
    const float* b_v   = (const float*)d_in[10];
    const float* w_p   = (const float*)d_in[11];
    const float* b_p   = (const float*)d_in[12];
    const float* ln_g  = (const float*)d_in[13];
    const float* ln_b  = (const float*)d_in[14];
    const float* w_ih  = (const float*)d_in[15];
    const float* w_hh  = (const float*)d_in[16];
    const float* b_ih  = (const float*)d_in[17];
    const float* b_hh  = (const float*)d_in[18];
    const float* w_c1  = (const float*)d_in[19];
    const float* b_c1  = (const float*)d_in[20];
    const float* w_c2  = (const float*)d_in[21];
    const float* b_c2  = (const float*)d_in[22];

    char* ws = (char*)d_ws;
    // ---- static region ----
    short* w1b  = (short*)(ws + 0);
    short* w2b  = (short*)(ws + 524288);
    short* wqb  = (short*)(ws + 1048576);
    short* wkb  = (short*)(ws + 2097152);
    short* wvb  = (short*)(ws + 3145728);
    short* wpb  = (short*)(ws + 5242880);
    short* wihb = (short*)(ws + 7340032);
    short* whhb = (short*)(ws + 11534336);
    short* wc1b = (short*)(ws + 19922944);
    float* bsum = (float*)(ws + 23068672);
    short* hs0  = (short*)(ws + 23085056);     // 32 KB
    short* hs1  = (short*)(ws + 23117824);     // 32 KB
    int*   arr  = (int*)  (ws + 23150592);     // 512 B
    float* a2   = (float*)(ws + 23150848);
    short* lpad = (short*)(ws + 23216384);
    // ---- dynamic region D0 = 40,026,368 ----
    const size_t D0 = 40026368u;
    short* xbf   = (short*)(ws + D0);
    short* h1bf  = (short*)(ws + D0 + 8388608);
    short* h2bf  = (short*)(ws + D0 + 16777216);
    short* qbf   = (short*)(ws + D0 + 25165824);
    short* kbf   = (short*)(ws + D0 + 41943040);
    short* vbf   = (short*)(ws + D0 + 58720256);
    short* vTbf  = (short*)(ws + D0 + 92274688);
    short* scb   = (short*)(ws + D0 + 58720256);   // 32 MB (vbf slot, dead after vT)
    short* obf   = (short*)(ws + D0 + 125829120);
    short* ybf   = (short*)(ws + D0 + 58720256);   // scb dead by then
    short* ylnbf = (short*)(ws + D0 + 67108864);
    short* igb   = (short*)(ws + D0 + 92274688);
    short* a1bf  = (short*)(ws + D0);

    hipMemsetAsync(lpad, 0, (size_t)8 * 1026 * 1024 * 2, stream);
    hipMemsetAsync(hs0, 0, 32768, stream);
    hipMemsetAsync(hs1, 0, 32768, stream);
    hipMemsetAsync(arr, 0, 512, stream);

    k_f32_to_bf16<<<dim3(4096), dim3(256), 0, stream>>>((const float4v*)x, (short4v*)xbf, 1048576);
    k_cvt_weights<<<dim3(4096), dim3(256), 0, stream>>>(
        (const float4v*)w_in1, (const float4v*)w_in2, (const float4v*)w_q, (const float4v*)w_k,
        (const float4v*)w_v, (const float4v*)w_p, (const float4v*)w_ih, (const float4v*)w_hh,
        (short4v*)w1b);
    k_wc1_tr<<<dim3((512 * 3072 + 255) / 256), dim3(256), 0, stream>>>(w_c1, wc1b);
    k_bias_sum<<<dim3(16), dim3(256), 0, stream>>>(b_ih, b_hh, bsum, 4096);

    gemm_bt(stream, xbf, w1b, nullptr, h1bf, b_in1, 8192, 512, 512, 512, 512, 512,
            1, 1, 0, 0, 0, 0, 0, 0, 1, 0);
    gemm_bt(stream, h1bf, w2b, nullptr, h2bf, b_in2, 8192, 512, 512, 512, 512, 512,
            1, 1, 0, 0, 0, 0, 0, 0, 0, 0);
    gemm_bt(stream, h2bf, wqb, nullptr, qbf, b_q, 8192, 1024, 512, 512, 512, 1024,
            1, 1, 0, 0, 0, 0, 0, 0, 0, 0);
    gemm_bt(stream, h2bf, wkb, nullptr, kbf, b_k, 8192, 1024, 512, 512, 512, 1024,
            1, 1, 0, 0, 0, 0, 0, 0, 0, 0);
    gemm_bt(stream, h2bf, wvb, nullptr, vbf, b_v, 8192, 2048, 512, 512, 512, 2048,
            1, 1, 0, 0, 0, 0, 0, 0, 0, 0);
    k_vT<<<dim3(16, 32, 32), dim3(256), 0, stream>>>(vbf, vTbf);

    // attention: 4 batches per iteration (z = 4 batches x 4 heads = 16)
    for (int bg = 0; bg < 2; ++bg) {
        const short* qb = qbf + (long)bg * 4194304;
        const short* kb = kbf + (long)bg * 4194304;
        gemm_bt(stream, qb, kb, nullptr, scb, nullptr, 1024, 1024, 256, 1024, 1024, 1024,
                16, 4, 256, 1048576, 256, 1048576, 1048576, 4194304, 0, 0);
        k_softmax_rows_bf16<<<dim3(16384), dim3(256), 0, stream>>>(scb);
        gemm_bt(stream, scb, vTbf + (long)bg * 8388608, nullptr, obf + (long)bg * 8388608, nullptr,
                1024, 512, 1024, 1024, 1024, 2048,
                16, 4, 1048576, 4194304, 524288, 2097152, 512, 2097152, 0, 0);
    }

    gemm_bt(stream, obf, wpb, nullptr, ybf, b_p, 8192, 512, 2048, 2048, 2048, 512,
            1, 1, 0, 0, 0, 0, 0, 0, 0, 0);
    k_layernorm<<<dim3(8192), dim3(256), 0, stream>>>(ybf, ln_g, ln_b, ylnbf);
    gemm_bt(stream, ylnbf, wihb, nullptr, igb, bsum, 8192, 4096, 512, 512, 512, 4096,
            1, 1, 0, 0, 0, 0, 0, 0, 0, 0);
    k_lstm<<<dim3(64), dim3(256), 0, stream>>>(whhb, igb, hs0, hs1, lpad, arr);
    gemm_bt(stream, lpad, wc1b, nullptr, a1bf, b_c1, 8192, 512, 3072, 1024, 3072, 512,
            1, 1, 0, 0, 0, 0, 0, 0, 2, 1);
    k_conv2<<<dim3(64), dim3(256), 0, stream>>>(a1bf, w_c2, b_c2, a2);
    k_feat<<<dim3(64), dim3(256), 0, stream>>>(a2, lpad, (float*)d_out);
    (void)in_sizes; (void)n_in; (void)out_size; (void)ws_size;
}